// Round 6
// baseline (891.284 us; speedup 1.0000x reference)
//
#include <hip/hip_runtime.h>

// Problem constants (fixed by reference)
#define NN   50000
#define DD   16
#define FFE  256
#define HH   8
#define DHH  32
#define RR   20
#define HOPN 10

typedef unsigned short u16;
typedef unsigned int   u32;
typedef __attribute__((ext_vector_type(8))) short  short8;   // 8 bf16 = 4 VGPRs
typedef __attribute__((ext_vector_type(4))) float  floatx4;

__device__ __forceinline__ float b2f(u16 u){ return __uint_as_float(((u32)u)<<16); }
__device__ __forceinline__ u16 f2b(float f){
  u32 x = __float_as_uint(f);
  u32 r = (x + 0x7fffu + ((x>>16)&1u)) >> 16;   // RNE
  return (u16)r;
}

// ---------------------------------------------------------------------------
// castw: one-off cast+transpose of value-path weights to bf16 [N][K] layout.
// ---------------------------------------------------------------------------
__global__ __launch_bounds__(256) void castw_kernel(
    const float* __restrict__ We, const float* __restrict__ W1,
    const float* __restrict__ W2,
    u16* __restrict__ Wet, u16* __restrict__ W1t, u16* __restrict__ W2t)
{
  int tid = blockIdx.x*256 + threadIdx.x;
  if (tid < 256*256) {                       // W_ent [256][256] -> Wet[n][k]
    int k = tid >> 8, n = tid & 255;
    Wet[n*256 + k] = f2b(We[tid]);
  } else if (tid < 256*256 + 256*1024) {     // W1 [256][1024] -> W1t[n][k]
    int s = tid - 65536;
    int k = s >> 10, n = s & 1023;
    W1t[n*256 + k] = f2b(W1[s]);
  } else if (tid < 589824) {                 // W2 [1024][256] -> W2t[n][k]
    int s = tid - 327680;
    int k = s >> 8, n = s & 255;
    W2t[n*1024 + k] = f2b(W2[s]);
  }
}

// ---------------------------------------------------------------------------
// prep: blocks 0..19 -> LN(rel_feat[r]) @ W_rel -> er[r,h]  (fp64, selection)
//       block 20     -> fold attn into Wc[256][16]: cols 0..7 = W_head·attn_h,
//                       cols 8..15 = W_tail·attn_t.
// ---------------------------------------------------------------------------
__global__ __launch_bounds__(256) void prep_kernel(
    const float* __restrict__ rel_feat,
    const float* __restrict__ W_head, const float* __restrict__ W_tail,
    const float* __restrict__ W_rel,
    const float* __restrict__ attn_h, const float* __restrict__ attn_t,
    const float* __restrict__ attn_r,
    const float* __restrict__ lng, const float* __restrict__ lnb,
    double* __restrict__ Wc, double* __restrict__ er)
{
  int t = threadIdx.x;
  if (blockIdx.x == RR) {
    for (int h = 0; h < HH; h++) {
      double sh = 0.0, st = 0.0;
      #pragma unroll
      for (int c = 0; c < DHH; c++) {
        int j = h*DHH + c;
        sh += (double)W_head[t*FFE + j] * (double)attn_h[j];
        st += (double)W_tail[t*FFE + j] * (double)attn_t[j];
      }
      Wc[t*16 + h]     = sh;
      Wc[t*16 + 8 + h] = st;
    }
    return;
  }
  int r = blockIdx.x;
  __shared__ double red[8];
  __shared__ double rln[256];
  double v = (double)rel_feat[r*FFE + t];
  double s = v, q = v*v;
  #pragma unroll
  for (int o = 32; o; o >>= 1) { s += __shfl_xor(s, o, 64); q += __shfl_xor(q, o, 64); }
  if ((t & 63) == 0) { red[t>>6] = s; red[4 + (t>>6)] = q; }
  __syncthreads();
  double stot = red[0]+red[1]+red[2]+red[3];
  double qtot = red[4]+red[5]+red[6]+red[7];
  double mean = stot * (1.0/256.0);
  double var  = qtot * (1.0/256.0) - mean*mean;
  double rstd = 1.0 / sqrt(var + 1e-5);
  rln[t] = (v - mean) * rstd * (double)lng[t] + (double)lnb[t];
  __syncthreads();
  double acc = 0.0;
  for (int k = 0; k < 256; k++) acc += rln[k] * (double)W_rel[k*FFE + t];
  double p = acc * (double)attn_r[t];
  #pragma unroll
  for (int o = 16; o; o >>= 1) p += __shfl_down(p, o, 32);
  if ((t & 31) == 0) er[r*HH + (t>>5)] = p;
}

// ---------------------------------------------------------------------------
// logits v3: zero LDS. One wave per ROW PAIR; lane l holds x-cols
// {l, l+64, l+128, l+192} in registers (straight from LN). Phase 2: lane
// accumulates all 16 outputs from Wc[k][0..15] (8 independent b128 L1
// loads per k), then 6-level fp64 butterfly. No xs staging, no bank
// conflicts, no per-iter exposed global latency chain.
// ---------------------------------------------------------------------------
__global__ __launch_bounds__(256) void logits_kernel(
    const float* __restrict__ ent,
    const float* __restrict__ lng, const float* __restrict__ lnb,
    const double* __restrict__ Wc,
    u16* __restrict__ xb, double* __restrict__ eh, double* __restrict__ et)
{
  int tid = threadIdx.x;
  int w = tid >> 6, l = tid & 63;
  int rowA = blockIdx.x*8 + w*2;
  int rowB = rowA + 1;
  float gg[4], bbv[4];
  #pragma unroll
  for (int j = 0; j < 4; j++) { gg[j] = lng[l + 64*j]; bbv[j] = lnb[l + 64*j]; }
  double xA[4], xB[4];
  #pragma unroll
  for (int j = 0; j < 4; j++) xA[j] = (double)ent[(size_t)rowA*FFE + l + 64*j];
  #pragma unroll
  for (int j = 0; j < 4; j++) xB[j] = (double)ent[(size_t)rowB*FFE + l + 64*j];
  double sA = xA[0]+xA[1]+xA[2]+xA[3];
  double sB = xB[0]+xB[1]+xB[2]+xB[3];
  double qA = xA[0]*xA[0]+xA[1]*xA[1]+xA[2]*xA[2]+xA[3]*xA[3];
  double qB = xB[0]*xB[0]+xB[1]*xB[1]+xB[2]*xB[2]+xB[3]*xB[3];
  #pragma unroll
  for (int o = 32; o; o >>= 1) {
    sA += __shfl_xor(sA, o, 64); qA += __shfl_xor(qA, o, 64);
    sB += __shfl_xor(sB, o, 64); qB += __shfl_xor(qB, o, 64);
  }
  double mA = sA * (1.0/256.0), mB = sB * (1.0/256.0);
  double vA = qA * (1.0/256.0) - mA*mA, vB = qB * (1.0/256.0) - mB*mB;
  double rsA = 1.0 / sqrt(vA + 1e-5), rsB = 1.0 / sqrt(vB + 1e-5);
  #pragma unroll
  for (int j = 0; j < 4; j++) {
    double yA = (xA[j]-mA)*rsA*(double)gg[j] + (double)bbv[j];
    double yB = (xB[j]-mB)*rsB*(double)gg[j] + (double)bbv[j];
    xA[j] = yA; xB[j] = yB;
    xb[(size_t)rowA*FFE + l + 64*j] = f2b((float)yA);
    xb[(size_t)rowB*FFE + l + 64*j] = f2b((float)yB);
  }
  double accA[16], accB[16];
  #pragma unroll
  for (int o = 0; o < 16; o++) { accA[o] = 0.0; accB[o] = 0.0; }
  #pragma unroll
  for (int j = 0; j < 4; j++) {
    int k = l + 64*j;
    const double2* wp = (const double2*)(Wc + (size_t)k*16);
    double wv[16];
    #pragma unroll
    for (int u = 0; u < 8; u++) { double2 tv = wp[u]; wv[2*u] = tv.x; wv[2*u+1] = tv.y; }
    #pragma unroll
    for (int o = 0; o < 16; o++) {
      accA[o] = fma(xA[j], wv[o], accA[o]);
      accB[o] = fma(xB[j], wv[o], accB[o]);
    }
  }
  #pragma unroll
  for (int o = 0; o < 16; o++) {
    #pragma unroll
    for (int off = 32; off; off >>= 1) {
      accA[o] += __shfl_xor(accA[o], off, 64);
      accB[o] += __shfl_xor(accB[o], off, 64);
    }
  }
  // lanes 0..15 store rowA's 16 outputs; lanes 16..31 store rowB's.
  #pragma unroll
  for (int o = 0; o < 16; o++) {
    if (l == o) {
      if (o < 8) eh[(size_t)rowA*HH + o] = accA[o];
      else       et[(size_t)rowA*HH + (o-8)] = accA[o];
    }
    if (l == 16 + o) {
      if (o < 8) eh[(size_t)rowB*HH + o] = accB[o];
      else       et[(size_t)rowB*HH + (o-8)] = accB[o];
    }
  }
}

// ---------------------------------------------------------------------------
// gemm: C[M,N] = A[M,K]bf16 @ B[N,K]bf16 (B pre-transposed), MFMA 16x16x32.
// 128x128 tile, BK=32, 256 threads (4 waves, each 32 rows x 128 cols).
// EPI 0: bf16 store. EPI 1: relu(v+bias) bf16. EPI 2: v+bias+feat+ent fp32.
// ---------------------------------------------------------------------------
template<int EPI>
__global__ __launch_bounds__(256) void gemm_kernel(
    const u16* __restrict__ A, const u16* __restrict__ B,
    const float* __restrict__ bias,
    const u16* __restrict__ feat, const float* __restrict__ ent,
    u16* __restrict__ Obf, float* __restrict__ Of,
    int M, int N, int K)
{
  __shared__ u16 As[128][40];
  __shared__ u16 Bs[128][40];
  int t = threadIdx.x;
  int i0 = blockIdx.x * 128;
  int n0 = blockIdx.y * 128;
  int w = t >> 6, l = t & 63;
  int cr = t >> 2;              // staging row 0..63 (and +64)
  int cc = (t & 3) * 8;         // staging k-offset {0,8,16,24}
  int ga0 = min(i0 + cr, M-1);  // clamp M-boundary reads (stores predicated)
  int ga1 = min(i0 + cr + 64, M-1);
  int gb0 = n0 + cr;
  int gb1 = n0 + cr + 64;
  floatx4 acc[2][8];
  #pragma unroll
  for (int mt = 0; mt < 2; mt++)
    #pragma unroll
    for (int nt = 0; nt < 8; nt++) acc[mt][nt] = (floatx4){0.f,0.f,0.f,0.f};
  int ln = l & 15, lq = (l >> 4) * 8;
  for (int k0 = 0; k0 < K; k0 += 32) {
    __syncthreads();
    *(uint4*)&As[cr][cc]      = *(const uint4*)&A[(size_t)ga0*K + k0 + cc];
    *(uint4*)&As[cr+64][cc]   = *(const uint4*)&A[(size_t)ga1*K + k0 + cc];
    *(uint4*)&Bs[cr][cc]      = *(const uint4*)&B[(size_t)gb0*K + k0 + cc];
    *(uint4*)&Bs[cr+64][cc]   = *(const uint4*)&B[(size_t)gb1*K + k0 + cc];
    __syncthreads();
    short8 bfr[8];
    #pragma unroll
    for (int nt = 0; nt < 8; nt++) bfr[nt] = *(const short8*)&Bs[nt*16 + ln][lq];
    #pragma unroll
    for (int mt = 0; mt < 2; mt++) {
      short8 afr = *(const short8*)&As[w*32 + mt*16 + ln][lq];
      #pragma unroll
      for (int nt = 0; nt < 8; nt++)
        acc[mt][nt] = __builtin_amdgcn_mfma_f32_16x16x32_bf16(afr, bfr[nt], acc[mt][nt], 0, 0, 0);
    }
  }
  int lr = (l >> 4) * 4;        // C/D layout: col=lane&15, row=(lane>>4)*4+reg
  #pragma unroll
  for (int mt = 0; mt < 2; mt++) {
    #pragma unroll
    for (int nt = 0; nt < 8; nt++) {
      int col = n0 + nt*16 + ln;
      #pragma unroll
      for (int r = 0; r < 4; r++) {
        int row = i0 + w*32 + mt*16 + lr + r;
        if (row < M) {
          float v = acc[mt][nt][r];
          if (EPI == 0) {
            Obf[(size_t)row*N + col] = f2b(v);
          } else if (EPI == 1) {
            v += bias[col];
            Obf[(size_t)row*N + col] = f2b(v > 0.f ? v : 0.f);
          } else {
            v += bias[col] + b2f(feat[(size_t)row*FFE + col]) + ent[(size_t)row*FFE + col];
            Of[(size_t)row*N + col] = v;
          }
        }
      }
    }
  }
}

// ---------------------------------------------------------------------------
// edge: per (i,h): e_d = leaky(eh[src]+et+er[rid]) in fp64; top-5 (+1 tie slot);
//       weights = exp(e-max)/sum_top5, prescaled by (1-ALPHA)=0.9.
// ---------------------------------------------------------------------------
__global__ __launch_bounds__(256) void edge_kernel(
    const int* __restrict__ src, const int* __restrict__ rid,
    const double* __restrict__ eh, const double* __restrict__ et,
    const double* __restrict__ er,
    int* __restrict__ idx6, float* __restrict__ w6)
{
  int tid = blockIdx.x*256 + threadIdx.x;
  if (tid >= NN*HH) return;
  int i = tid >> 3, h = tid & 7;
  double bet = et[tid];
  double e[16]; int sj[16];
  #pragma unroll
  for (int d = 0; d < 16; d++) {
    int s = src[i*DD + d];
    int rv = rid[i*DD + d];
    sj[d] = s;
    double v = eh[s*HH + h] + bet + er[rv*HH + h];
    e[d] = (v > 0.0) ? v : 0.2 * v;
  }
  u32 mask = 0; double vs[5]; int js[5];
  #pragma unroll
  for (int k = 0; k < 5; k++) {
    double best = -1e300; int bj = 0, bd = 0;
    #pragma unroll
    for (int d = 0; d < 16; d++) {
      bool c = (((mask>>d)&1u) == 0u) && (e[d] > best);
      if (c) { best = e[d]; bj = sj[d]; bd = d; }
    }
    mask |= (1u << bd); vs[k] = best; js[k] = bj;
  }
  double kth = vs[4];
  int j6 = 0; bool f6 = false;
  #pragma unroll
  for (int d = 0; d < 16; d++) {
    if ((((mask>>d)&1u) == 0u) && (e[d] == kth) && !f6) { j6 = sj[d]; f6 = true; }
  }
  float m0 = (float)vs[0];
  float ex[5], ssum = 0.f;
  #pragma unroll
  for (int k = 0; k < 5; k++) { ex[k] = __expf((float)vs[k] - m0); ssum += ex[k]; }
  float inv = 0.9f / ssum;
  long base = (long)tid * 6;
  #pragma unroll
  for (int k = 0; k < 5; k++) { idx6[base+k] = js[k]; w6[base+k] = ex[k]*inv; }
  idx6[base+5] = j6; w6[base+5] = f6 ? ex[4]*inv : 0.f;
}

// ---------------------------------------------------------------------------
// diff: one hop. 2 nodes/block, u32-vectorized: lane handles a bf16 PAIR so
// one wave-load covers 4 distinct (j,h) 64-B segments. Tie slot (w==0)
// skipped. 25000 blocks => TLP-driven latency hiding (round-4 lesson).
// ---------------------------------------------------------------------------
__global__ __launch_bounds__(256) void diff_kernel(
    const u16* __restrict__ fold, const u16* __restrict__ fe,
    const int* __restrict__ idx6, const float* __restrict__ w6,
    u16* __restrict__ fnew)
{
  int tid = threadIdx.x;
  int i = blockIdx.x*2 + (tid >> 7);
  int t2 = tid & 127;            // u32 column index within row
  int h = t2 >> 4, c2 = t2 & 15; // 16 u32 lanes per head
  const u32* fold32 = (const u32*)fold;
  const u32* fe32   = (const u32*)fe;
  u32* fnew32 = (u32*)fnew;
  long eb = ((long)i*HH + h) * 6;
  u32 fv = fe32[(size_t)i*128 + t2];
  float acc0 = 0.1f * b2f((u16)(fv & 0xffff));
  float acc1 = 0.1f * b2f((u16)(fv >> 16));
  #pragma unroll
  for (int k = 0; k < 5; k++) {
    int j = idx6[eb + k];
    float w = w6[eb + k];
    u32 v = fold32[(size_t)j*128 + h*16 + c2];
    acc0 += w * b2f((u16)(v & 0xffff));
    acc1 += w * b2f((u16)(v >> 16));
  }
  float w5 = w6[eb + 5];
  if (w5 != 0.f) {
    int j = idx6[eb + 5];
    u32 v = fold32[(size_t)j*128 + h*16 + c2];
    acc0 += w5 * b2f((u16)(v & 0xffff));
    acc1 += w5 * b2f((u16)(v >> 16));
  }
  fnew32[(size_t)i*128 + t2] = (u32)f2b(acc0) | ((u32)f2b(acc1) << 16);
}

// ---------------------------------------------------------------------------
// ln_ff: y = bf16( LN(feat+ent) ).  One wave per row, lane holds 4 elems.
// ---------------------------------------------------------------------------
__global__ __launch_bounds__(256) void ln_ff_kernel(
    const u16* __restrict__ feat, const float* __restrict__ ent,
    const float* __restrict__ g, const float* __restrict__ b,
    u16* __restrict__ y)
{
  int w = threadIdx.x >> 6, l = threadIdx.x & 63;
  int row = blockIdx.x*4 + w;
  float4 e4 = *(const float4*)&ent[row*FFE + l*4];
  ushort4 fv = *(const ushort4*)&feat[row*FFE + l*4];
  float v0 = b2f(fv.x)+e4.x, v1 = b2f(fv.y)+e4.y;
  float v2 = b2f(fv.z)+e4.z, v3 = b2f(fv.w)+e4.w;
  float s = v0+v1+v2+v3;
  float q = v0*v0 + v1*v1 + v2*v2 + v3*v3;
  #pragma unroll
  for (int o = 32; o; o >>= 1) { s += __shfl_xor(s, o, 64); q += __shfl_xor(q, o, 64); }
  float mean = s * (1.f/256.f);
  float var  = q * (1.f/256.f) - mean*mean;
  float rstd = rsqrtf(var + 1e-5f);
  float4 g4 = *(const float4*)&g[l*4];
  float4 b4 = *(const float4*)&b[l*4];
  ushort4 o4;
  o4.x = f2b((v0-mean)*rstd*g4.x + b4.x);
  o4.y = f2b((v1-mean)*rstd*g4.y + b4.y);
  o4.z = f2b((v2-mean)*rstd*g4.z + b4.z);
  o4.w = f2b((v3-mean)*rstd*g4.w + b4.w);
  *(ushort4*)&y[row*FFE + l*4] = o4;
}

// ---------------------------------------------------------------------------
extern "C" void kernel_launch(void* const* d_in, const int* in_sizes, int n_in,
                              void* d_out, int out_size, void* d_ws, size_t ws_size,
                              hipStream_t stream)
{
  const float* ent      = (const float*)d_in[0];
  const float* rel      = (const float*)d_in[1];
  const float* W_head   = (const float*)d_in[2];
  const float* W_tail   = (const float*)d_in[3];
  const float* W_ent    = (const float*)d_in[4];
  const float* W_rel    = (const float*)d_in[5];
  const float* attn_h   = (const float*)d_in[6];
  const float* attn_t   = (const float*)d_in[7];
  const float* attn_r   = (const float*)d_in[8];
  const float* ln_ent_g = (const float*)d_in[9];
  const float* ln_ent_b = (const float*)d_in[10];
  const float* ln_rel_g = (const float*)d_in[11];
  const float* ln_rel_b = (const float*)d_in[12];
  const float* ln_ff_g  = (const float*)d_in[13];
  const float* ln_ff_b  = (const float*)d_in[14];
  const float* W1       = (const float*)d_in[15];
  const float* b1       = (const float*)d_in[16];
  const float* W2       = (const float*)d_in[17];
  const float* b2       = (const float*)d_in[18];
  const int* src        = (const int*)d_in[19];
  const int* rid        = (const int*)d_in[20];
  float* out = (float*)d_out;

  // Workspace layout. h1 (102.4 MB) ALIASES [0, 102.4 MB): all tensors there
  // are dead before gemm1 runs. fB (final feat) lives OUTSIDE the alias.
  char* w = (char*)d_ws;
  double* er64 = (double*)(w + 0);            // 1.3 KB   (dead after edge)
  double* Wc   = (double*)(w + 4096);         // 32 KB    (dead after logits)
  double* eh64 = (double*)(w + 36864);        // 3.2 MB   (dead after edge)
  double* et64 = (double*)(w + 3236864);      // 3.2 MB
  u16*    xb   = (u16*)  (w + 6436864);       // 25.6 MB  (dead after proj)
  u16*    fe   = (u16*)  (w + 32036864);      // 25.6 MB  (dead after hops)
  u16*    fA   = (u16*)  (w + 57636864);      // 25.6 MB  (dead after hops)
  int*    idx6 = (int*)  (w + 83236864);      // 9.6 MB   (dead after hops)
  float*  w6   = (float*)(w + 92836864);      // 9.6 MB   (dead after hops)
  u16*    h1   = (u16*)  (w + 0);             // 102.4 MB alias, gemm1->gemm2
  u16*    fB   = (u16*)  (w + 102436864);     // 25.6 MB  (final feat, live to end)
  u16*    y    = (u16*)  (w + 128036864);     // 25.6 MB
  u16*    Wet  = (u16*)  (w + 153636864);     // 128 KB
  u16*    W1t  = (u16*)  (w + 153767936);     // 512 KB
  u16*    W2t  = (u16*)  (w + 154292224);     // 512 KB  (end 154,816,512)

  castw_kernel<<<2304, 256, 0, stream>>>(W_ent, W1, W2, Wet, W1t, W2t);
  prep_kernel<<<RR+1, 256, 0, stream>>>(rel, W_head, W_tail, W_rel,
                                        attn_h, attn_t, attn_r,
                                        ln_rel_g, ln_rel_b, Wc, er64);
  logits_kernel<<<NN/8, 256, 0, stream>>>(ent, ln_ent_g, ln_ent_b, Wc,
                                          xb, eh64, et64);
  // proj: fe = xb @ Wet
  {
    dim3 g((NN + 127)/128, 2);
    gemm_kernel<0><<<g, 256, 0, stream>>>(xb, Wet, nullptr, nullptr, nullptr,
                                          fe, nullptr, NN, 256, 256);
  }
  edge_kernel<<<(NN*HH + 255)/256, 256, 0, stream>>>(src, rid, eh64, et64, er64,
                                                     idx6, w6);
  // 10 hops, one dispatch each: 25000 blocks => latency hiding via TLP.
  const u16* cur = fe;
  u16* bufs[2] = { fA, fB };
  for (int hop = 0; hop < HOPN; hop++) {
    u16* nxt = bufs[hop & 1];
    diff_kernel<<<NN/2, 256, 0, stream>>>(cur, fe, idx6, w6, nxt);
    cur = nxt;                                 // final cur == fB (10 hops)
  }
  ln_ff_kernel<<<NN/4, 256, 0, stream>>>(cur, ent, ln_ff_g, ln_ff_b, y);
  {
    dim3 g((NN + 127)/128, 8);                 // h1 = relu(y@W1 + b1)
    gemm_kernel<1><<<g, 256, 0, stream>>>(y, W1t, b1, nullptr, nullptr,
                                          h1, nullptr, NN, 1024, 256);
  }
  {
    dim3 g((NN + 127)/128, 2);                 // out = h1@W2 + b2 + feat + ent
    gemm_kernel<2><<<g, 256, 0, stream>>>(h1, W2t, b2, cur, ent,
                                          nullptr, out, NN, 256, 1024);
  }
}